// Round 16
// baseline (3695.713 us; speedup 1.0000x reference)
//
#include <hip/hip_runtime.h>
#include <cstdint>

// ---- problem constants ----
#define NT  4
#define NB  32
#define NC  512
#define NCH 2048
#define NN  196
#define NM  (NB * NN)   // 6272 columns = 98*64
#define NMB (NM / 8)    // 784 column-bytes
#define NH  8

struct GP {
    const float *q_bn_s, *q_bn_b, *k_bn_s, *k_bn_b;
    const float *proj_b, *proj_bn_s, *proj_bn_b;
    const float *mlp1_b, *mlp1_bn_s, *mlp1_bn_b;
    const float *mlp2_b, *mlp2_bn_s, *mlp2_bn_b;
    const float *wqkT, *wprojT, *wmlp1T, *wmlp2T;  // [K][O] transposed weights
    const float *xT;                                // [T][C][M] permuted input
    float *xy;                                      // [C][M] x + y_spike (per t)
    float *v_q, *v_k, *v_y, *v_h1, *v_h2, *v_attn;  // LIF states
    // TRANSPOSED bit-planes [mB][C]: byte (mB,c) = cols mB*8..+7 of channel c
    unsigned char *q_bt, *k_bt, *h1_bt, *attn_bt;   // [NMB][512/512/2048/8]
    float *out;
    int t;
};

// Exact-f32 LIF step (bitwise-validated vs reference in R2-R15).
__device__ __forceinline__ float lif_step(float z, float v_old, float vth, int& sp) {
    float d = __fsub_rn(z, v_old);
    float h = __fmul_rn(d, 0.5f);
    float v = __fadd_rn(v_old, h);
    sp = (v >= vth) ? 1 : 0;
    return sp ? 0.0f : v;
}

typedef const void __attribute__((address_space(1))) gas_t;
typedef void __attribute__((address_space(3))) las_t;
__device__ __forceinline__ void gl_lds16(const float* g, float* l) {
    __builtin_amdgcn_global_load_lds((gas_t*)g, (las_t*)l, 16, 0, 0);
}
template <int N>
__device__ __forceinline__ void vmwait() {
    if constexpr (N == 0)      asm volatile("s_waitcnt vmcnt(0)" ::: "memory");
    else if constexpr (N == 3) asm volatile("s_waitcnt vmcnt(3)" ::: "memory");
    else if constexpr (N == 4) asm volatile("s_waitcnt vmcnt(4)" ::: "memory");
}
__device__ __forceinline__ void vm0() {
    asm volatile("s_waitcnt vmcnt(0)" ::: "memory");
}
__device__ __forceinline__ void lgkm0() {
    asm volatile("s_waitcnt lgkmcnt(0)" ::: "memory");
}

// ---------------- pre-kernels ----------------

// dst[c*ldD + offD + o] = src[o*K + c]   (32x32 LDS tiles)
__global__ __launch_bounds__(256) void trw_k(const float* __restrict__ src,
                                             float* __restrict__ dst,
                                             int K, int ldD, int offD) {
    __shared__ float tle[32][33];
    const int c0 = blockIdx.x * 32, o0 = blockIdx.y * 32;
    const int tx = threadIdx.x & 31, ty = threadIdx.x >> 5;
#pragma unroll
    for (int r = 0; r < 4; ++r)
        tle[ty + r * 8][tx] = src[(size_t)(o0 + ty + r * 8) * K + c0 + tx];
    __syncthreads();
#pragma unroll
    for (int r = 0; r < 4; ++r)
        dst[(size_t)(c0 + ty + r * 8) * ldD + offD + o0 + tx] = tle[tx][ty + r * 8];
}

// xT[t][c][b][n] = x[t][b][c][n]
__global__ __launch_bounds__(64) void permx_k(const float* __restrict__ x,
                                              float* __restrict__ xT) {
    const int id = blockIdx.x;         // t*16384 + c*32 + b
    const int b = id & 31;
    const int c = (id >> 5) & 511;
    const int t = id >> 14;
    const float* s = x + ((size_t)(t * NB + b) * NC + c) * NN;
    float* d = xT + ((size_t)(t * NC + c) * NB + b) * NN;
    for (int n = threadIdx.x; n < NN; n += 64) d[n] = s[n];
}

// attn LIF: thread = col-byte mB, all 8 heads; SWAR popcount over qT row.
// (R11-proven, refcheck'd R11-R13.)
__global__ __launch_bounds__(256) void attn_k(GP gp) {
    const int mB = blockIdx.x * 256 + threadIdx.x;
    if (mB >= NMB) return;
    const unsigned* qr = (const unsigned*)(gp.q_bt + (size_t)mB * NC);  // 128 dwords
    unsigned outB[8];
#pragma unroll
    for (int h = 0; h < NH; ++h) {
        unsigned a[8];
#pragma unroll
        for (int j = 0; j < 8; ++j) a[j] = 0;
#pragma unroll
        for (int d = 0; d < 16; ++d) {
            const unsigned w = qr[h * 16 + d];
#pragma unroll
            for (int j = 0; j < 8; ++j) a[j] += (w >> j) & 0x01010101u;
        }
        float* vr = gp.v_attn + (size_t)h * NM + mB * 8;
        unsigned ob = 0;
#pragma unroll
        for (int j = 0; j < 8; ++j) {
            unsigned s = a[j] + (a[j] >> 16);
            s = (s + (s >> 8)) & 0xff;                   // sum of 64 bits
            float v = gp.t ? vr[j] : 0.0f;
            int sp;
            v = lif_step((float)s, v, 0.5f, sp);          // dyadic-exact
            vr[j] = v;
            ob |= (unsigned)sp << j;
        }
        outB[h] = ob;
    }
    uint2 w;
    w.x = outB[0] | (outB[1] << 8) | (outB[2] << 16) | (outB[3] << 24);
    w.y = outB[4] | (outB[5] << 8) | (outB[6] << 16) | (outB[7] << 24);
    *(uint2*)(gp.attn_bt + (size_t)mB * 8) = w;
}

// ---------------- unfused GEMM + BN + LIF (MODE 0 = q&k, MODE 2 = mlp1) ----------------
// R8-proven loop; R11-proven TRANSPOSED bit-plane epilogue (u32 = 4 o-bytes).
template <int MODE>
__global__ __launch_bounds__(64) void gemm_unf(GP gp) {
    constexpr int LDA = (MODE == 0) ? 1024 : 2048;
    constexpr int BK = 16;
    constexpr int NIT = 512 / BK;             // 32

    __shared__ float As[2][BK][32];           // 4 KB
    __shared__ float Xs[2][BK][64];           // 8 KB

    const int lane = threadIdx.x;
    const int to = lane & 7;
    const int tn = lane >> 3;
    const int m0 = blockIdx.x * 64;
    const int ot = blockIdx.y;
    const int o0 = ot * 32;
    const int mb = m0 + tn * 8;
    const int mbB = (m0 >> 3) + tn;

    const float* wA = (MODE == 0) ? gp.wqkT : gp.wmlp1T;
    const float* xf = (MODE == 0) ? gp.xT + (size_t)gp.t * NC * NM : gp.xy;

    auto stageA = [&](int buf, int s) {
#pragma unroll
        for (int r = 0; r < 2; ++r)
            gl_lds16(wA + (size_t)(s * BK + r * 8 + (lane >> 3)) * LDA + o0 + (lane & 7) * 4,
                     &As[buf][r * 8][0]);
    };
    auto stageX = [&](int buf, int s) {
#pragma unroll
        for (int r = 0; r < 4; ++r)
            gl_lds16(xf + (size_t)(s * BK + r * 4 + (lane >> 4)) * NM + m0 + (lane & 15) * 4,
                     &Xs[buf][r * 4][0]);
    };

    float acc[4][8];
#pragma unroll
    for (int i = 0; i < 4; ++i)
#pragma unroll
        for (int j = 0; j < 8; ++j) acc[i][j] = 0.0f;

    auto compute = [&](int cur) {
#pragma unroll 4
        for (int kk = 0; kk < BK; ++kk) {
            const float4 av = *(const float4*)&As[cur][kk][to * 4];
            const float4 x0 = *(const float4*)&Xs[cur][kk][tn * 8];
            const float4 x1 = *(const float4*)&Xs[cur][kk][tn * 8 + 4];
            const float a4[4] = {av.x, av.y, av.z, av.w};
            const float x8[8] = {x0.x, x0.y, x0.z, x0.w, x1.x, x1.y, x1.z, x1.w};
#pragma unroll
            for (int i = 0; i < 4; ++i)
#pragma unroll
                for (int j = 0; j < 8; ++j)
                    acc[i][j] = __fadd_rn(acc[i][j], __fmul_rn(a4[i], x8[j]));
        }
    };

    stageA(0, 0); stageX(0, 0);
    vm0();
#pragma unroll 1
    for (int it = 0; it < NIT; ++it) {
        const int cur = it & 1;
        const bool more = (it + 1 < NIT);
        if (more) { stageA(cur ^ 1, it + 1); stageX(cur ^ 1, it + 1); }
        compute(cur);
        if (more) vm0();
    }

    // epilogue: BN + LIF; bits -> TRANSPOSED [mB][C] planes (u32 = 4 o-bytes)
    if constexpr (MODE == 0) {
        const bool isq = (ot < 16);
        const float* bs = isq ? gp.q_bn_s : gp.k_bn_s;
        const float* bbv = isq ? gp.q_bn_b : gp.k_bn_b;
        float* vb = isq ? gp.v_q : gp.v_k;
        unsigned char* sb = isq ? gp.q_bt : gp.k_bt;
        const int ob = (ot & 15) * 32;
        unsigned pw = 0;
#pragma unroll
        for (int i = 0; i < 4; ++i) {
            const int oo = ob + to * 4 + i;
            const float sc = bs[oo], bc = bbv[oo];
            float* vr = vb + (size_t)oo * NM + mb;
            float vv[8];
            if (gp.t) {
                const float4 v0 = *(const float4*)vr, v1 = *(const float4*)(vr + 4);
                vv[0] = v0.x; vv[1] = v0.y; vv[2] = v0.z; vv[3] = v0.w;
                vv[4] = v1.x; vv[5] = v1.y; vv[6] = v1.z; vv[7] = v1.w;
            } else {
#pragma unroll
                for (int j = 0; j < 8; ++j) vv[j] = 0.0f;
            }
            unsigned pb = 0;
#pragma unroll
            for (int j = 0; j < 8; ++j) {
                const float z = __fadd_rn(__fmul_rn(acc[i][j], sc), bc);
                int sp;
                vv[j] = lif_step(z, vv[j], 1.0f, sp);
                pb |= (unsigned)sp << j;
            }
            *(float4*)vr = make_float4(vv[0], vv[1], vv[2], vv[3]);
            *(float4*)(vr + 4) = make_float4(vv[4], vv[5], vv[6], vv[7]);
            pw |= pb << (i * 8);
        }
        *(unsigned*)(sb + (size_t)mbB * NC + ob + to * 4) = pw;
    } else {
        const int ob = ot * 32;
        unsigned pw = 0;
#pragma unroll
        for (int i = 0; i < 4; ++i) {
            const int o = ob + to * 4 + i;
            const float bi = gp.mlp1_b[o], sc = gp.mlp1_bn_s[o], bc = gp.mlp1_bn_b[o];
            float* vr = gp.v_h1 + (size_t)o * NM + mb;
            float vv[8];
            if (gp.t) {
                const float4 v0 = *(const float4*)vr, v1 = *(const float4*)(vr + 4);
                vv[0] = v0.x; vv[1] = v0.y; vv[2] = v0.z; vv[3] = v0.w;
                vv[4] = v1.x; vv[5] = v1.y; vv[6] = v1.z; vv[7] = v1.w;
            } else {
#pragma unroll
                for (int j = 0; j < 8; ++j) vv[j] = 0.0f;
            }
            unsigned pb = 0;
#pragma unroll
            for (int j = 0; j < 8; ++j) {
                const float z = __fadd_rn(__fmul_rn(__fadd_rn(acc[i][j], bi), sc), bc);
                int sp;
                vv[j] = lif_step(z, vv[j], 1.0f, sp);
                pb |= (unsigned)sp << j;
            }
            *(float4*)vr = make_float4(vv[0], vv[1], vv[2], vv[3]);
            *(float4*)(vr + 4) = make_float4(vv[4], vv[5], vv[6], vv[7]);
            pw |= pb << (i * 8);
        }
        *(unsigned*)(gp.h1_bt + (size_t)mbB * NCH + ob + to * 4) = pw;
    }
}

// ---------------- fused GEMM + BN + LIF (MODE 1 = proj, MODE 3 = mlp2) ----------------
// 32o x 32m, per-thread 4x4, R10/R15 ring skeleton (4-buffer, stage-ahead-2,
// counted vmcnt). NEW: X stays PACKED BITS. Per K-step: 64 B of X bits staged
// global->reg->ds_write (R10-proven idiom); compute reads ONE uint4 per ITER
// and expands nibbles in-register (~9 VALU/kk). LDS/kk = 16 B (A only) =
// 1.06 B/FMA -> off the 2.0 B/FMA cap that held R9/R10/R15 at 48-50%.
template <int MODE>
__global__ __launch_bounds__(64) void gemm_fus(GP gp) {
    constexpr int K_TOT = (MODE == 3) ? 2048 : 512;
    constexpr int BK = 16;
    constexpr int NIT = K_TOT / BK;           // 32 or 128 (divisible by 4)
    constexpr int STW = (MODE == 1) ? 4 : 3;  // VM ops per stage

    __shared__ float As[4][BK][32];           // 8 KB
    __shared__ unsigned char Xb[4][4][16];    // 256 B packed X bits

    const int lane = threadIdx.x;
    const int to = lane & 7;                  // 4 rows each
    const int tn = lane >> 3;                 // 4 cols each
    const int m0 = blockIdx.x * 32;
    const int o0 = blockIdx.y * 32;
    const int mb = m0 + tn * 4;
    const int mB0 = m0 >> 3;                  // first col-byte of tile (4 total)
    const unsigned nib = 4u * (tn & 1);       // nibble of this thread's 4 cols

    const float* wA = (MODE == 1) ? gp.wprojT : gp.wmlp2T;
    const unsigned char* xbt = (MODE == 1) ? gp.k_bt : gp.h1_bt;  // [mB][K_TOT]

    const int l4 = lane & 15;
    const int mbi = l4 >> 2;                  // staging: col-byte 0..3
    const int rr = l4 & 3;                    // staging: row-quad 0..3

    auto stageA = [&](int buf, int s) {
#pragma unroll
        for (int r = 0; r < 2; ++r)
            gl_lds16(wA + (size_t)(s * BK + r * 8 + (lane >> 3)) * 512 + o0 + (lane & 7) * 4,
                     &As[buf][r * 8][0]);
    };
    // all 64 lanes load (lanes 16+ duplicate lane&15): no divergence
    auto loadB = [&](int s) -> uint2 {
        uint2 r;
        r.x = *(const unsigned*)(xbt + (size_t)(mB0 + mbi) * K_TOT + s * BK + rr * 4);
        if constexpr (MODE == 1)
            r.y = gp.attn_bt[(size_t)(mB0 + mbi) * 8 + (s >> 2)];   // head = s>>2
        else
            r.y = 0;
        return r;
    };
    auto flushB = [&](int buf, uint2 xb) {
        // x_one = k & attn: byte-replicated AND, exact ({0,1} product)
        const unsigned w = (MODE == 1) ? (xb.x & (xb.y * 0x01010101u)) : xb.x;
        *(unsigned*)&Xb[buf][mbi][rr * 4] = w;   // 4-way same-addr, same value
    };

    float acc[4][4];
#pragma unroll
    for (int i = 0; i < 4; ++i)
#pragma unroll
        for (int j = 0; j < 4; ++j) acc[i][j] = 0.0f;

    auto compute = [&](int cb) {
        const uint4 xq = *(const uint4*)&Xb[cb][tn >> 1][0];  // this thread's byte, 16 rows
        const unsigned xs[4] = {xq.x >> nib, xq.y >> nib, xq.z >> nib, xq.w >> nib};
#pragma unroll
        for (int kk = 0; kk < BK; ++kk) {
            const float4 av = *(const float4*)&As[cb][kk][to * 4];
            const float a4[4] = {av.x, av.y, av.z, av.w};
            const unsigned wsel = xs[kk >> 2] >> ((kk & 3) * 8);
            float x4[4];
#pragma unroll
            for (int j = 0; j < 4; ++j) x4[j] = (float)((wsel >> j) & 1u);
#pragma unroll
            for (int i = 0; i < 4; ++i)
#pragma unroll
                for (int j = 0; j < 4; ++j)
                    acc[i][j] = __fmaf_rn(a4[i], x4[j], acc[i][j]);
        }
    };

    // ---- 4-buffer ring, stage-ahead 2, counted vmcnt (R10-proven) ----
    uint2 sl0, sl1;
    stageA(0, 0); sl0 = loadB(0);
    stageA(1, 1); sl1 = loadB(1);
    vmwait<STW>();                        // stage0 retired (stage1 in flight)
    flushB(0, sl0);
    lgkm0();

    auto body = [&](int i, int cb, uint2& sStage, uint2& sFlush) {
        if (i + 2 < NIT) { stageA((cb + 2) & 3, i + 2); sStage = loadB(i + 2); }
        compute(cb);
        if (i + 1 < NIT) {
            if (NIT - 1 - i >= 2) vmwait<STW>(); else vmwait<0>();
            flushB((cb + 1) & 3, sFlush);
            lgkm0();
        }
    };
#pragma unroll 1
    for (int i = 0; i < NIT; i += 4) {
        body(i + 0, 0, sl0, sl1);
        body(i + 1, 1, sl1, sl0);
        body(i + 2, 2, sl0, sl1);
        body(i + 3, 3, sl1, sl0);
    }

    // ---- epilogue: BN + LIF, exact reference op order (4 rows x 4 cols) ----
    if constexpr (MODE == 1) {
#pragma unroll
        for (int i = 0; i < 4; ++i) {
            const int o = o0 + to * 4 + i;
            const float bi = gp.proj_b[o], sc = gp.proj_bn_s[o], bc = gp.proj_bn_b[o];
            float* vr = gp.v_y + (size_t)o * NM + mb;
            const float4 vld = gp.t ? *(const float4*)vr : make_float4(0, 0, 0, 0);
            const float4 xv4 = *(const float4*)(gp.xT + ((size_t)gp.t * NC + o) * NM + mb);
            float vv[4] = {vld.x, vld.y, vld.z, vld.w};
            const float xvv[4] = {xv4.x, xv4.y, xv4.z, xv4.w};
            float xyo[4];
#pragma unroll
            for (int j = 0; j < 4; ++j) {
                const float z = __fadd_rn(__fmul_rn(__fadd_rn(acc[i][j], bi), sc), bc);
                int sp;
                vv[j] = lif_step(z, vv[j], 1.0f, sp);
                xyo[j] = __fadd_rn(xvv[j], (float)sp);   // residual x + y
            }
            *(float4*)vr = make_float4(vv[0], vv[1], vv[2], vv[3]);
            *(float4*)(gp.xy + (size_t)o * NM + mb) = make_float4(xyo[0], xyo[1], xyo[2], xyo[3]);
        }
    } else {  // MODE 3
        const int b = mb / NN;                // mb%4==0, NN%4==0 -> same b for 4 cols
        const int n = mb - b * NN;
#pragma unroll
        for (int i = 0; i < 4; ++i) {
            const int o = o0 + to * 4 + i;
            const float bi = gp.mlp2_b[o], sc = gp.mlp2_bn_s[o], bc = gp.mlp2_bn_b[o];
            float* vr = gp.v_h2 + (size_t)o * NM + mb;
            const float4 vld = gp.t ? *(const float4*)vr : make_float4(0, 0, 0, 0);
            const float4 xyv = *(const float4*)(gp.xy + (size_t)o * NM + mb);
            float vv[4] = {vld.x, vld.y, vld.z, vld.w};
            const float xyf[4] = {xyv.x, xyv.y, xyv.z, xyv.w};
            float ov[4];
#pragma unroll
            for (int j = 0; j < 4; ++j) {
                const float z = __fadd_rn(__fmul_rn(__fadd_rn(acc[i][j], bi), sc), bc);
                int sp;
                vv[j] = lif_step(z, vv[j], 1.0f, sp);
                ov[j] = __fadd_rn(xyf[j], (float)sp);
            }
            *(float4*)&gp.out[(((size_t)gp.t * NB + b) * NC + o) * NN + n] =
                make_float4(ov[0], ov[1], ov[2], ov[3]);
            *(float4*)vr = make_float4(vv[0], vv[1], vv[2], vv[3]);
        }
    }
}

extern "C" void kernel_launch(void* const* d_in, const int* in_sizes, int n_in,
                              void* d_out, int out_size, void* d_ws, size_t ws_size,
                              hipStream_t stream) {
    const float* x       = (const float*)d_in[0];
    const float* q_w     = (const float*)d_in[1];
    const float* k_w     = (const float*)d_in[4];
    const float* proj_w  = (const float*)d_in[7];
    const float* mlp1_w  = (const float*)d_in[11];
    const float* mlp2_w  = (const float*)d_in[15];

    GP gp;
    gp.q_bn_s = (const float*)d_in[2];  gp.q_bn_b = (const float*)d_in[3];
    gp.k_bn_s = (const float*)d_in[5];  gp.k_bn_b = (const float*)d_in[6];
    gp.proj_b = (const float*)d_in[8];  gp.proj_bn_s = (const float*)d_in[9];  gp.proj_bn_b = (const float*)d_in[10];
    gp.mlp1_b = (const float*)d_in[12]; gp.mlp1_bn_s = (const float*)d_in[13]; gp.mlp1_bn_b = (const float*)d_in[14];
    gp.mlp2_b = (const float*)d_in[16]; gp.mlp2_bn_s = (const float*)d_in[17]; gp.mlp2_bn_b = (const float*)d_in[18];
    gp.out = (float*)d_out;

    char* ws = (char*)d_ws;
    size_t off = 0;
    auto alloc = [&](size_t bytes) -> void* {
        void* r = ws + off;
        off += (bytes + 255) & ~(size_t)255;
        return r;
    };
    float* wqkT   = (float*)alloc((size_t)512 * 1024 * 4);
    float* wprojT = (float*)alloc((size_t)512 * 512 * 4);
    float* wmlp1T = (float*)alloc((size_t)512 * 2048 * 4);
    float* wmlp2T = (float*)alloc((size_t)2048 * 512 * 4);
    float* xT     = (float*)alloc((size_t)NT * NC * NM * 4);
    gp.xy     = (float*)alloc((size_t)NC * NM * 4);
    gp.v_q    = (float*)alloc((size_t)NC * NM * 4);
    gp.v_k    = (float*)alloc((size_t)NC * NM * 4);
    gp.v_y    = (float*)alloc((size_t)NC * NM * 4);
    gp.v_h2   = (float*)alloc((size_t)NC * NM * 4);
    gp.v_h1   = (float*)alloc((size_t)NCH * NM * 4);
    gp.v_attn = (float*)alloc((size_t)NH * NM * 4);
    gp.q_bt   = (unsigned char*)alloc((size_t)NMB * NC);
    gp.k_bt   = (unsigned char*)alloc((size_t)NMB * NC);
    gp.h1_bt  = (unsigned char*)alloc((size_t)NMB * NCH);
    gp.attn_bt= (unsigned char*)alloc((size_t)NMB * NH);
    gp.wqkT = wqkT; gp.wprojT = wprojT; gp.wmlp1T = wmlp1T; gp.wmlp2T = wmlp2T;
    gp.xT = xT;

    // one-time (per call) layout transforms
    trw_k<<<dim3(16, 16), 256, 0, stream>>>(q_w,    wqkT,   512,  1024, 0);
    trw_k<<<dim3(16, 16), 256, 0, stream>>>(k_w,    wqkT,   512,  1024, 512);
    trw_k<<<dim3(16, 16), 256, 0, stream>>>(proj_w, wprojT, 512,  512,  0);
    trw_k<<<dim3(16, 64), 256, 0, stream>>>(mlp1_w, wmlp1T, 512,  2048, 0);
    trw_k<<<dim3(64, 16), 256, 0, stream>>>(mlp2_w, wmlp2T, 2048, 512,  0);
    permx_k<<<NT * NC * NB, 64, 0, stream>>>(x, xT);

    for (int t = 0; t < NT; ++t) {
        gp.t = t;
        gemm_unf<0><<<dim3(98, 32), 64, 0, stream>>>(gp);   // q,k -> bit-planes
        attn_k<<<dim3(4), 256, 0, stream>>>(gp);            // attn LIF -> bit-plane
        gemm_fus<1><<<dim3(196, 16), 64, 0, stream>>>(gp);  // proj -> v_y, xy
        gemm_unf<2><<<dim3(98, 64), 64, 0, stream>>>(gp);   // mlp1 -> h1 bit-plane
        gemm_fus<3><<<dim3(196, 16), 64, 0, stream>>>(gp);  // mlp2 -> out
    }
}

// Round 17
// 2519.719 us; speedup vs baseline: 1.4667x; 1.4667x over previous
//
#include <hip/hip_runtime.h>
#include <cstdint>

// ---- problem constants ----
#define NT  4
#define NB  32
#define NC  512
#define NCH 2048
#define NN  196
#define NM  (NB * NN)   // 6272 columns = 98*64
#define NH  8

struct GP {
    const float *q_bn_s, *q_bn_b, *k_bn_s, *k_bn_b;
    const float *proj_b, *proj_bn_s, *proj_bn_b;
    const float *mlp1_b, *mlp1_bn_s, *mlp1_bn_b;
    const float *mlp2_b, *mlp2_bn_s, *mlp2_bn_b;
    const float *wqkT, *wprojT, *wmlp1T, *wmlp2T;  // [K][O] transposed weights
    const float *xT;                                // [T][C][M] permuted input
    float *xy;                                      // [C][M] x + y_spike (per t)
    float *v_q, *v_k, *v_y, *v_h1, *v_h2, *v_attn;  // LIF states, [C][M]
    unsigned char *q_sp, *k_sp, *h1_sp, *attn_sp;   // binary spikes (bytes)
    float *out;
    int t;
};

// Exact-f32 LIF step (bitwise-validated vs reference in R2-R16).
__device__ __forceinline__ float lif_step(float z, float v_old, float vth, int& sp) {
    float d = __fsub_rn(z, v_old);
    float h = __fmul_rn(d, 0.5f);
    float v = __fadd_rn(v_old, h);
    sp = (v >= vth) ? 1 : 0;
    return sp ? 0.0f : v;
}

typedef const void __attribute__((address_space(1))) gas_t;
typedef void __attribute__((address_space(3))) las_t;
__device__ __forceinline__ void gl_lds16(const float* g, float* l) {
    __builtin_amdgcn_global_load_lds((gas_t*)g, (las_t*)l, 16, 0, 0);
}
__device__ __forceinline__ void vm0() {
    asm volatile("s_waitcnt vmcnt(0)" ::: "memory");
}
__device__ __forceinline__ void vm3() {
    asm volatile("s_waitcnt vmcnt(3)" ::: "memory");
}
__device__ __forceinline__ void lgkm0() {
    asm volatile("s_waitcnt lgkmcnt(0)" ::: "memory");
}

// ---------------- pre-kernels ----------------

// dst[c*ldD + offD + o] = src[o*K + c]   (32x32 LDS tiles)
__global__ __launch_bounds__(256) void trw_k(const float* __restrict__ src,
                                             float* __restrict__ dst,
                                             int K, int ldD, int offD) {
    __shared__ float tle[32][33];
    const int c0 = blockIdx.x * 32, o0 = blockIdx.y * 32;
    const int tx = threadIdx.x & 31, ty = threadIdx.x >> 5;
#pragma unroll
    for (int r = 0; r < 4; ++r)
        tle[ty + r * 8][tx] = src[(size_t)(o0 + ty + r * 8) * K + c0 + tx];
    __syncthreads();
#pragma unroll
    for (int r = 0; r < 4; ++r)
        dst[(size_t)(c0 + ty + r * 8) * ldD + offD + o0 + tx] = tle[tx][ty + r * 8];
}

// xT[t][c][b][n] = x[t][b][c][n]
__global__ __launch_bounds__(64) void permx_k(const float* __restrict__ x,
                                              float* __restrict__ xT) {
    const int id = blockIdx.x;         // t*16384 + c*32 + b
    const int b = id & 31;
    const int c = (id >> 5) & 511;
    const int t = id >> 14;
    const float* s = x + ((size_t)(t * NB + b) * NC + c) * NN;
    float* d = xT + ((size_t)(t * NC + c) * NB + b) * NN;
    for (int n = threadIdx.x; n < NN; n += 64) d[n] = s[n];
}

// attn LIF: per (h,m): integer sum of 64 q-spike bytes; LIF vth=0.5
__global__ __launch_bounds__(256) void attn_k(GP gp) {
    const int m = blockIdx.x * 256 + threadIdx.x;
    const int h = blockIdx.y;
    if (m >= NM) return;
    const unsigned char* q = gp.q_sp + (size_t)h * 64 * NM + m;
    int s = 0;
#pragma unroll 8
    for (int d = 0; d < 64; ++d) s += q[(size_t)d * NM];
    float v = gp.t ? gp.v_attn[(size_t)h * NM + m] : 0.0f;
    int sp;
    v = lif_step((float)s, v, 0.5f, sp);
    gp.v_attn[(size_t)h * NM + m] = v;
    gp.attn_sp[(size_t)h * NM + m] = (unsigned char)sp;
}

// ---------------- fused GEMM + BN + LIF ----------------
// ONE wave per block, wave-private LDS, ZERO barriers, vmcnt-only sync.
// Unfused (MODE 0/2): 2-buffer stage-ahead-1 (compute 2048cyc covers latency).
// Fused (MODE 1/3): 4-buffer ring, stage-ahead-2, counted vmcnt --
//   compute is only 512cyc/iter so 1-deep couldn't hide ~900cyc HBM latency
//   (R8: 46% VALUBusy); Xs rows padded to 36 floats to kill the 16-way
//   ds_write bank conflict (R8: 6.4e6 conflict cycles).
// MODE 0: q&k (O=1024,K=512), X=xT[t], 32o x 64m   unfused mul+add
// MODE 1: proj (O=512,K=512), X=k_sp&attn_sp (u8), 32o x 32m  fma (exact)
// MODE 2: mlp1 (O=2048,K=512), X=xy,   32o x 64m   unfused mul+add
// MODE 3: mlp2 (O=512,K=2048), X=h1_sp (u8), 32o x 32m  fma; writes out
template <int MODE>
__global__ __launch_bounds__(64) void gemm_lif(GP gp) {
    constexpr bool FUSED = (MODE == 1 || MODE == 3);
    constexpr int K_TOT = (MODE == 3) ? 2048 : 512;
    constexpr int LDA = (MODE == 0) ? 1024 : (MODE == 2) ? 2048 : 512;
    constexpr int BK = 16;
    constexpr int NIT = K_TOT / BK;           // 32 or 128 (divisible by 4)
    constexpr int MT = FUSED ? 32 : 64;       // m-tile
    constexpr int RN = FUSED ? 4 : 8;         // cols per thread
    constexpr int NBUF = FUSED ? 4 : 2;
    constexpr int XP = FUSED ? 36 : MT;       // fused: pad rows to 144B

    __shared__ float As[NBUF][BK][32];
    __shared__ float Xs[NBUF][BK][XP];

    const int lane = threadIdx.x;
    const int to = lane & 7;                  // o-group: rows to*4..+4
    const int tn = lane >> 3;                 // col-group: cols tn*RN..+RN
    const int m0 = blockIdx.x * MT;
    const int ot = blockIdx.y;                // o-tile (32 channels)
    const int o0 = ot * 32;
    const int mb = m0 + tn * RN;

    const float* wA = (MODE == 0) ? gp.wqkT : (MODE == 1) ? gp.wprojT
                    : (MODE == 2) ? gp.wmlp1T : gp.wmlp2T;
    const float* xf = (MODE == 0) ? gp.xT + (size_t)gp.t * NC * NM : gp.xy;

    auto stageA = [&](int buf, int s) {
#pragma unroll
        for (int r = 0; r < 2; ++r)
            gl_lds16(wA + (size_t)(s * BK + r * 8 + (lane >> 3)) * LDA + o0 + (lane & 7) * 4,
                     &As[buf][r * 8][0]);
    };
    auto stageXf = [&](int buf, int s) {
#pragma unroll
        for (int r = 0; r < 4; ++r)
            gl_lds16(xf + (size_t)(s * BK + r * 4 + (lane >> 4)) * NM + m0 + (lane & 15) * 4,
                     &Xs[buf][r * 4][0]);
    };
    // fused byte staging: 16x32 bytes, 4 B/lane (1-2 vmcnt ops)
    const int xrow = lane >> 2;               // 0..15
    const int xcb = (lane & 3) * 8;           // unused for fused path
    (void)xcb;
    const int xby = lane & 3;
    auto loadF = [&](int s, unsigned& k, unsigned& a) {
        const int c = s * BK + xrow;
        if constexpr (MODE == 1) {
            k = *(const unsigned*)(gp.k_sp + (size_t)c * NM + m0 + xby * 8);
            a = *(const unsigned*)(gp.attn_sp + (size_t)(c >> 6) * NM + m0 + xby * 8);
        } else {
            k = *(const unsigned*)(gp.h1_sp + (size_t)c * NM + m0 + xby * 8);
            (void)a;
        }
    };
    auto loadF2 = [&](int s, unsigned& k, unsigned& a) {
        const int c = s * BK + xrow;
        if constexpr (MODE == 1) {
            k = *(const unsigned*)(gp.k_sp + (size_t)c * NM + m0 + xby * 8 + 4);
            a = *(const unsigned*)(gp.attn_sp + (size_t)(c >> 6) * NM + m0 + xby * 8 + 4);
        } else {
            k = *(const unsigned*)(gp.h1_sp + (size_t)c * NM + m0 + xby * 8 + 4);
            (void)a;
        }
    };
    auto flushW = [&](int buf, unsigned k, unsigned a, int off) {
        const unsigned w = (MODE == 1) ? (k & a) : k;   // {0,1} bytes: AND == product
        float* d = &Xs[buf][xrow][xby * 8 + off];
        float4 f;
        f.x = (float)(unsigned char)(w);
        f.y = (float)(unsigned char)(w >> 8);
        f.z = (float)(unsigned char)(w >> 16);
        f.w = (float)(w >> 24);
        *(float4*)d = f;
    };

    float acc[4][RN];
#pragma unroll
    for (int i = 0; i < 4; ++i)
#pragma unroll
        for (int j = 0; j < RN; ++j) acc[i][j] = 0.0f;

    auto compute = [&](int cur) {
        if constexpr (!FUSED) {
#pragma unroll 4
            for (int kk = 0; kk < BK; ++kk) {
                const float4 av = *(const float4*)&As[cur][kk][to * 4];
                const float4 x0 = *(const float4*)&Xs[cur][kk][tn * 8];
                const float4 x1 = *(const float4*)&Xs[cur][kk][tn * 8 + 4];
                const float a4[4] = {av.x, av.y, av.z, av.w};
                const float x8[8] = {x0.x, x0.y, x0.z, x0.w, x1.x, x1.y, x1.z, x1.w};
#pragma unroll
                for (int i = 0; i < 4; ++i)
#pragma unroll
                    for (int j = 0; j < 8; ++j)
                        acc[i][j] = __fadd_rn(acc[i][j], __fmul_rn(a4[i], x8[j]));
            }
        } else {
#pragma unroll 8
            for (int kk = 0; kk < BK; ++kk) {
                const float4 av = *(const float4*)&As[cur][kk][to * 4];
                const float4 xv = *(const float4*)&Xs[cur][kk][tn * 4];
                const float a4[4] = {av.x, av.y, av.z, av.w};
                const float x4[4] = {xv.x, xv.y, xv.z, xv.w};
#pragma unroll
                for (int i = 0; i < 4; ++i)
#pragma unroll
                    for (int j = 0; j < 4; ++j)
                        acc[i][j] = __fmaf_rn(a4[i], x4[j], acc[i][j]);
            }
        }
    };

    if constexpr (!FUSED) {
        // ---- unfused: 2-buffer, stage-ahead 1 (proven R8/R9) ----
        stageA(0, 0); stageXf(0, 0);
        vm0();
#pragma unroll 1
        for (int it = 0; it < NIT; ++it) {
            const int cur = it & 1;
            const bool more = (it + 1 < NIT);
            if (more) { stageA(cur ^ 1, it + 1); stageXf(cur ^ 1, it + 1); }
            compute(cur);
            if (more) vm0();
        }
    } else {
        // ---- fused: 4-buffer ring, stage-ahead 2, counted vmcnt ----
        unsigned k0a, a0a, k0b, a0b, k1a, a1a, k1b, a1b;
        stageA(0, 0); loadF(0, k0a, a0a); loadF2(0, k0b, a0b);
        stageA(1, 1); loadF(1, k1a, a1a); loadF2(1, k1b, a1b);
        if constexpr (MODE == 1) {
            asm volatile("s_waitcnt vmcnt(6)" ::: "memory");
        } else {
            asm volatile("s_waitcnt vmcnt(4)" ::: "memory");
        }
        flushW(0, k0a, a0a, 0); flushW(0, k0b, a0b, 4);
        lgkm0();

        auto body = [&](int i, int cb,
                        unsigned& kSa, unsigned& aSa, unsigned& kSb, unsigned& aSb,
                        unsigned& kFa, unsigned& aFa, unsigned& kFb, unsigned& aFb) {
            if (i + 2 < NIT) { stageA((cb + 2) & 3, i + 2); loadF(i + 2, kSa, aSa); loadF2(i + 2, kSb, aSb); }
            compute(cb);
            if (i + 1 < NIT) {
                if (NIT - 1 - i >= 2) {
                    if constexpr (MODE == 1) {
                        asm volatile("s_waitcnt vmcnt(6)" ::: "memory");
                    } else {
                        asm volatile("s_waitcnt vmcnt(4)" ::: "memory");
                    }
                } else {
                    vm0();
                }
                flushW((cb + 1) & 3, kFa, aFa, 0); flushW((cb + 1) & 3, kFb, aFb, 4);
                lgkm0();
            }
        };
#pragma unroll 1
        for (int i = 0; i < NIT; i += 4) {
            body(i + 0, 0, k0a, a0a, k0b, a0b, k1a, a1a, k1b, a1b);
            body(i + 1, 1, k1a, a1a, k1b, a1b, k0a, a0a, k0b, a0b);
            body(i + 2, 2, k0a, a0a, k0b, a0b, k1a, a1a, k1b, a1b);
            body(i + 3, 3, k1a, a1a, k1b, a1b, k0a, a0a, k0b, a0b);
        }
    }

    // ---- epilogue: BN + LIF, exact reference op order ----
    if constexpr (MODE == 0) {
        const bool isq = (ot < 16);
        const float* bs = isq ? gp.q_bn_s : gp.k_bn_s;
        const float* bbv = isq ? gp.q_bn_b : gp.k_bn_b;
        float* vb = isq ? gp.v_q : gp.v_k;
        unsigned char* sb = isq ? gp.q_sp : gp.k_sp;
        const int ob = (ot & 15) * 32;
#pragma unroll
        for (int i = 0; i < 4; ++i) {
            const int oo = ob + to * 4 + i;
            const float sc = bs[oo], bc = bbv[oo];
            float* vr = vb + (size_t)oo * NM + mb;
            float vv[8];
            if (gp.t) {
                const float4 v0 = *(const float4*)vr, v1 = *(const float4*)(vr + 4);
                vv[0] = v0.x; vv[1] = v0.y; vv[2] = v0.z; vv[3] = v0.w;
                vv[4] = v1.x; vv[5] = v1.y; vv[6] = v1.z; vv[7] = v1.w;
            } else {
#pragma unroll
                for (int j = 0; j < 8; ++j) vv[j] = 0.0f;
            }
            unsigned int pk[2] = {0, 0};
#pragma unroll
            for (int j = 0; j < 8; ++j) {
                const float z = __fadd_rn(__fmul_rn(acc[i][j], sc), bc);
                int sp;
                vv[j] = lif_step(z, vv[j], 1.0f, sp);
                pk[j >> 2] |= (unsigned)sp << ((j & 3) * 8);
            }
            *(float4*)vr = make_float4(vv[0], vv[1], vv[2], vv[3]);
            *(float4*)(vr + 4) = make_float4(vv[4], vv[5], vv[6], vv[7]);
            *(unsigned int*)(sb + (size_t)oo * NM + mb) = pk[0];
            *(unsigned int*)(sb + (size_t)oo * NM + mb + 4) = pk[1];
        }
    } else if constexpr (MODE == 2) {
        const int ob = ot * 32;
#pragma unroll
        for (int i = 0; i < 4; ++i) {
            const int o = ob + to * 4 + i;
            const float bi = gp.mlp1_b[o], sc = gp.mlp1_bn_s[o], bc = gp.mlp1_bn_b[o];
            float* vr = gp.v_h1 + (size_t)o * NM + mb;
            float vv[8];
            if (gp.t) {
                const float4 v0 = *(const float4*)vr, v1 = *(const float4*)(vr + 4);
                vv[0] = v0.x; vv[1] = v0.y; vv[2] = v0.z; vv[3] = v0.w;
                vv[4] = v1.x; vv[5] = v1.y; vv[6] = v1.z; vv[7] = v1.w;
            } else {
#pragma unroll
                for (int j = 0; j < 8; ++j) vv[j] = 0.0f;
            }
            unsigned int pk[2] = {0, 0};
#pragma unroll
            for (int j = 0; j < 8; ++j) {
                const float z = __fadd_rn(__fmul_rn(__fadd_rn(acc[i][j], bi), sc), bc);
                int sp;
                vv[j] = lif_step(z, vv[j], 1.0f, sp);
                pk[j >> 2] |= (unsigned)sp << ((j & 3) * 8);
            }
            *(float4*)vr = make_float4(vv[0], vv[1], vv[2], vv[3]);
            *(float4*)(vr + 4) = make_float4(vv[4], vv[5], vv[6], vv[7]);
            *(unsigned int*)(gp.h1_sp + (size_t)o * NM + mb) = pk[0];
            *(unsigned int*)(gp.h1_sp + (size_t)o * NM + mb + 4) = pk[1];
        }
    } else if constexpr (MODE == 1) {
#pragma unroll
        for (int i = 0; i < 4; ++i) {
            const int o = ot * 32 + to * 4 + i;
            const float bi = gp.proj_b[o], sc = gp.proj_bn_s[o], bc = gp.proj_bn_b[o];
            float* vr = gp.v_y + (size_t)o * NM + mb;
            const float4 vld = gp.t ? *(const float4*)vr : make_float4(0, 0, 0, 0);
            const float4 xv4 = *(const float4*)(gp.xT + ((size_t)gp.t * NC + o) * NM + mb);
            float vv[4] = {vld.x, vld.y, vld.z, vld.w};
            const float xvv[4] = {xv4.x, xv4.y, xv4.z, xv4.w};
            float xyo[4];
#pragma unroll
            for (int j = 0; j < 4; ++j) {
                const float z = __fadd_rn(__fmul_rn(__fadd_rn(acc[i][j], bi), sc), bc);
                int sp;
                vv[j] = lif_step(z, vv[j], 1.0f, sp);
                xyo[j] = __fadd_rn(xvv[j], (float)sp);   // residual x + y
            }
            *(float4*)vr = make_float4(vv[0], vv[1], vv[2], vv[3]);
            *(float4*)(gp.xy + (size_t)o * NM + mb) = make_float4(xyo[0], xyo[1], xyo[2], xyo[3]);
        }
    } else {  // MODE 3
        const int b = mb / NN;                // mb%4==0, NN%4==0 -> same b for 4 cols
        const int n = mb - b * NN;
#pragma unroll
        for (int i = 0; i < 4; ++i) {
            const int o = ot * 32 + to * 4 + i;
            const float bi = gp.mlp2_b[o], sc = gp.mlp2_bn_s[o], bc = gp.mlp2_bn_b[o];
            float* vr = gp.v_h2 + (size_t)o * NM + mb;
            const float4 vld = gp.t ? *(const float4*)vr : make_float4(0, 0, 0, 0);
            const float4 xyv = *(const float4*)(gp.xy + (size_t)o * NM + mb);
            float vv[4] = {vld.x, vld.y, vld.z, vld.w};
            const float xyf[4] = {xyv.x, xyv.y, xyv.z, xyv.w};
            float ov[4];
#pragma unroll
            for (int j = 0; j < 4; ++j) {
                const float z = __fadd_rn(__fmul_rn(__fadd_rn(acc[i][j], bi), sc), bc);
                int sp;
                vv[j] = lif_step(z, vv[j], 1.0f, sp);
                ov[j] = __fadd_rn(xyf[j], (float)sp);
            }
            *(float4*)&gp.out[(((size_t)gp.t * NB + b) * NC + o) * NN + n] =
                make_float4(ov[0], ov[1], ov[2], ov[3]);
            *(float4*)vr = make_float4(vv[0], vv[1], vv[2], vv[3]);
        }
    }
}

extern "C" void kernel_launch(void* const* d_in, const int* in_sizes, int n_in,
                              void* d_out, int out_size, void* d_ws, size_t ws_size,
                              hipStream_t stream) {
    const float* x       = (const float*)d_in[0];
    const float* q_w     = (const float*)d_in[1];
    const float* k_w     = (const float*)d_in[4];
    const float* proj_w  = (const float*)d_in[7];
    const float* mlp1_w  = (const float*)d_in[11];
    const float* mlp2_w  = (const float*)d_in[15];

    GP gp;
    gp.q_bn_s = (const float*)d_in[2];  gp.q_bn_b = (const float*)d_in[3];
    gp.k_bn_s = (const float*)d_in[5];  gp.k_bn_b = (const float*)d_in[6];
    gp.proj_b = (const float*)d_in[8];  gp.proj_bn_s = (const float*)d_in[9];  gp.proj_bn_b = (const float*)d_in[10];
    gp.mlp1_b = (const float*)d_in[12]; gp.mlp1_bn_s = (const float*)d_in[13]; gp.mlp1_bn_b = (const float*)d_in[14];
    gp.mlp2_b = (const float*)d_in[16]; gp.mlp2_bn_s = (const float*)d_in[17]; gp.mlp2_bn_b = (const float*)d_in[18];
    gp.out = (float*)d_out;

    char* ws = (char*)d_ws;
    size_t off = 0;
    auto alloc = [&](size_t bytes) -> void* {
        void* r = ws + off;
        off += (bytes + 255) & ~(size_t)255;
        return r;
    };
    float* wqkT   = (float*)alloc((size_t)512 * 1024 * 4);
    float* wprojT = (float*)alloc((size_t)512 * 512 * 4);
    float* wmlp1T = (float*)alloc((size_t)512 * 2048 * 4);
    float* wmlp2T = (float*)alloc((size_t)2048 * 512 * 4);
    float* xT     = (float*)alloc((size_t)NT * NC * NM * 4);
    gp.xy     = (float*)alloc((size_t)NC * NM * 4);
    gp.v_q    = (float*)alloc((size_t)NC * NM * 4);
    gp.v_k    = (float*)alloc((size_t)NC * NM * 4);
    gp.v_y    = (float*)alloc((size_t)NC * NM * 4);
    gp.v_h2   = (float*)alloc((size_t)NC * NM * 4);
    gp.v_h1   = (float*)alloc((size_t)NCH * NM * 4);
    gp.v_attn = (float*)alloc((size_t)NH * NM * 4);
    gp.q_sp   = (unsigned char*)alloc((size_t)NC * NM);
    gp.k_sp   = (unsigned char*)alloc((size_t)NC * NM);
    gp.h1_sp  = (unsigned char*)alloc((size_t)NCH * NM);
    gp.attn_sp= (unsigned char*)alloc((size_t)NH * NM);
    gp.wqkT = wqkT; gp.wprojT = wprojT; gp.wmlp1T = wmlp1T; gp.wmlp2T = wmlp2T;
    gp.xT = xT;

    // one-time (per call) layout transforms
    trw_k<<<dim3(16, 16), 256, 0, stream>>>(q_w,    wqkT,   512,  1024, 0);
    trw_k<<<dim3(16, 16), 256, 0, stream>>>(k_w,    wqkT,   512,  1024, 512);
    trw_k<<<dim3(16, 16), 256, 0, stream>>>(proj_w, wprojT, 512,  512,  0);
    trw_k<<<dim3(16, 64), 256, 0, stream>>>(mlp1_w, wmlp1T, 512,  2048, 0);
    trw_k<<<dim3(64, 16), 256, 0, stream>>>(mlp2_w, wmlp2T, 2048, 512,  0);
    permx_k<<<NT * NC * NB, 64, 0, stream>>>(x, xT);

    for (int t = 0; t < NT; ++t) {
        gp.t = t;
        gemm_lif<0><<<dim3(98, 32), 64, 0, stream>>>(gp);   // q,k -> byte spikes
        attn_k<<<dim3(25, NH), 256, 0, stream>>>(gp);       // attn LIF
        gemm_lif<1><<<dim3(196, 16), 64, 0, stream>>>(gp);  // proj -> v_y, xy
        gemm_lif<2><<<dim3(98, 64), 64, 0, stream>>>(gp);   // mlp1 -> h1 bytes
        gemm_lif<3><<<dim3(196, 16), 64, 0, stream>>>(gp);  // mlp2 -> out
    }
}